// Round 5
// baseline (45.034 us; speedup 1.0000x reference)
//
#include <hip/hip_runtime.h>
#include <stdint.h>

// Problem constants (fixed by setup_inputs: bs=8, n=4096, c=256, pool=1024)
#define BATCH 8
#define NPTS  4096
#define CH    256
#define QN    1024

// ---- scan kernel: 1024 threads = 16 waves, 1 query/wave, 512 blocks ----
#define SBLOCK 1024
#define SQPB   16
#define SBLOCKS_PER_BATCH (QN / SQPB)   // 64 -> grid 512, 2 blocks/CU

__device__ __forceinline__ float fmul(float a, float b) { return __fmul_rn(a, b); }
__device__ __forceinline__ float fadd(float a, float b) { return __fadd_rn(a, b); }

// reference-exact distance: ((-2*((xx+yy)+zz)) + q_cand) + q_query, no FMA
__device__ __forceinline__ float cdist(const float4 vq, const float4 v) {
  float dot = fadd(fadd(fmul(vq.x, v.x), fmul(vq.y, v.y)), fmul(vq.z, v.z));
  return fadd(fadd(fmul(-2.0f, dot), v.w), vq.w);
}

// order-preserving float->u32 map, idx in low bits -> unique sortable key.
// (-0.0 cannot occur: all cancellations produce +0.0 in RN.)
__device__ __forceinline__ uint64_t mkkey(float d, uint32_t c) {
  uint32_t bb = __float_as_uint(d);
  bb ^= (uint32_t)((int32_t)bb >> 31) | 0x80000000u;
  return ((uint64_t)bb << 32) | c;
}

__device__ __forceinline__ void cswap(uint64_t& lo, uint64_t& hi) {
  uint64_t mn = hi < lo ? hi : lo;
  uint64_t mx = hi < lo ? lo : hi;
  lo = mn; hi = mx;
}

// wave-min of u64: 4 DPP row_ror steps (VALU pipe) then ^16/^32 via shfl.
__device__ __forceinline__ uint64_t wave_min(uint64_t x) {
#define DPP_MIN_STEP(CTRL)                                                     \
  {                                                                            \
    uint32_t lo = (uint32_t)x, hi = (uint32_t)(x >> 32);                       \
    uint32_t rl = (uint32_t)__builtin_amdgcn_update_dpp((int)lo, (int)lo,      \
                                                        CTRL, 0xF, 0xF, false);\
    uint32_t rh = (uint32_t)__builtin_amdgcn_update_dpp((int)hi, (int)hi,      \
                                                        CTRL, 0xF, 0xF, false);\
    uint64_t o = ((uint64_t)rh << 32) | rl;                                    \
    x = o < x ? o : x;                                                         \
  }
  DPP_MIN_STEP(0x121)  // row_ror:1
  DPP_MIN_STEP(0x122)  // row_ror:2
  DPP_MIN_STEP(0x124)  // row_ror:4
  DPP_MIN_STEP(0x128)  // row_ror:8
#undef DPP_MIN_STEP
  { uint64_t o = (uint64_t)__shfl_xor((long long)x, 16, 64); x = o < x ? o : x; }
  { uint64_t o = (uint64_t)__shfl_xor((long long)x, 32, 64); x = o < x ? o : x; }
  return x;
}

__shared__ float4 sv[NPTS];   // 64 KB: x,y,z,|v|^2

__global__ __launch_bounds__(SBLOCK) void knn_scan_kernel(
    const float* __restrict__ verts,   // [BATCH, NPTS, 3]
    const int*   __restrict__ sidx,    // [QN]
    int4*        __restrict__ nbr,     // [BATCH*QN] neighbor indices (d_ws)
    float*       __restrict__ outV)    // [BATCH, QN, 3]
{
  const int batch = blockIdx.x / SBLOCKS_PER_BATCH;
  const int qblk  = blockIdx.x % SBLOCKS_PER_BATCH;
  const float* vb = verts + (size_t)batch * (NPTS * 3);

  // stage vertices + squared norm into LDS
  for (int c = threadIdx.x; c < NPTS; c += SBLOCK) {
    float x = vb[c * 3 + 0];
    float y = vb[c * 3 + 1];
    float z = vb[c * 3 + 2];
    float q = fadd(fadd(fmul(x, x), fmul(y, y)), fmul(z, z));
    sv[c] = make_float4(x, y, z, q);
  }
  __syncthreads();

  const int wave = threadIdx.x >> 6;
  const int lane = threadIdx.x & 63;
  const int i = qblk * SQPB + wave;          // query slot in [0, QN)
  const float4 vq = sv[sidx[i]];             // broadcast read

  // per-lane top-2 of (d:f32, idx), strict-< insert == lexicographic (d,idx)
  float    d0 = __builtin_inff(), d1 = __builtin_inff();
  uint32_t i0 = 0, i1 = 0;
#pragma unroll 16
  for (int t = 0; t < NPTS / 64; ++t) {
    float4 v = sv[lane + t * 64];
    const uint32_t c = lane + t * 64;
    float d = cdist(vq, v);
    bool lt = d < d1;
    d1 = lt ? d : d1;
    i1 = lt ? c : i1;
    bool sw = d1 < d0;
    float    td = d0;  uint32_t ti = i0;
    d0 = sw ? d1 : d0;  i0 = sw ? i1 : i0;
    d1 = sw ? td : d1;  i1 = sw ? ti : i1;
  }

  // wave merge: 5 rounds of "min key strictly greater than prev"
  uint64_t k0 = mkkey(d0, i0);
  uint64_t k1 = mkkey(d1, i1);
  uint64_t prev = 0, nb1 = 0, nb2 = 0, nb3 = 0, nb4 = 0;
#pragma unroll
  for (int r = 0; r < 5; ++r) {
    uint64_t cand = k0 > prev ? k0 : (k1 > prev ? k1 : ~0ull);
    cand = wave_min(cand);
    if (r == 1) nb1 = cand;
    if (r == 2) nb2 = cand;
    if (r == 3) nb3 = cand;
    if (r == 4) nb4 = cand;
    prev = cand;
  }
  // exactness guard: all per-lane drops are > k1; if any lane's k1 < merged
  // 5th, rescan exactly (cold, ~0.2% of waves)
  if (__any(k1 < nb4)) {
    uint64_t b0 = ~0ull, b1 = ~0ull, b2 = ~0ull, b3 = ~0ull, b4 = ~0ull;
    for (int t = 0; t < NPTS / 64; ++t) {
      float4 v = sv[lane + t * 64];
      uint64_t key = mkkey(cdist(vq, v), lane + t * 64);
      b4 = key < b4 ? key : b4;
      cswap(b3, b4); cswap(b2, b3); cswap(b1, b2); cswap(b0, b1);
    }
    prev = 0;
#pragma unroll
    for (int r = 0; r < 5; ++r) {
      uint64_t cand = b0 > prev ? b0
                    : b1 > prev ? b1
                    : b2 > prev ? b2
                    : b3 > prev ? b3
                    : b4 > prev ? b4 : ~0ull;
      cand = wave_min(cand);
      if (r == 1) nb1 = cand;
      if (r == 2) nb2 = cand;
      if (r == 3) nb3 = cand;
      if (r == 4) nb4 = cand;
      prev = cand;
    }
  }

  if (lane == 0) {
    nbr[(size_t)batch * QN + i] = make_int4((int)(uint32_t)nb1,
                                            (int)(uint32_t)nb2,
                                            (int)(uint32_t)nb3,
                                            (int)(uint32_t)nb4);
  }
  if (lane < 3) {
    float val = lane == 0 ? vq.x : (lane == 1 ? vq.y : vq.z);
    outV[((size_t)batch * QN + i) * 3 + lane] = val;
  }
}

// ---- gather kernel: pure memory burst, 4 queries/block, no LDS ----
#define GBLOCK 256
#define GQPB   (GBLOCK / 64)   // 4 queries per block

__global__ __launch_bounds__(GBLOCK) void knn_gather_kernel(
    const float* __restrict__ feat,    // [BATCH, NPTS, CH]
    const int4*  __restrict__ nbr,     // [BATCH*QN]
    float*       __restrict__ outF)    // [BATCH, QN, CH]
{
  const int gq   = blockIdx.x * GQPB + (threadIdx.x >> 6);  // 0..8191
  const int lane = threadIdx.x & 63;
  const int4 nb  = nbr[gq];            // same addr all lanes -> broadcast
  const int batch = gq >> 10;          // QN = 1024
  const float* fb = feat + (size_t)batch * NPTS * CH;
  const int col = lane * 4;            // 64 lanes * 4 = 256 channels

  float4 f1 = *(const float4*)(fb + (size_t)nb.x * CH + col);
  float4 f2 = *(const float4*)(fb + (size_t)nb.y * CH + col);
  float4 f3 = *(const float4*)(fb + (size_t)nb.z * CH + col);
  float4 f4 = *(const float4*)(fb + (size_t)nb.w * CH + col);
  float4 r;
  r.x = fmaxf(fmaxf(f1.x, f2.x), fmaxf(f3.x, f4.x));
  r.y = fmaxf(fmaxf(f1.y, f2.y), fmaxf(f3.y, f4.y));
  r.z = fmaxf(fmaxf(f1.z, f2.z), fmaxf(f3.z, f4.z));
  r.w = fmaxf(fmaxf(f1.w, f2.w), fmaxf(f3.w, f4.w));
  *(float4*)(outF + (size_t)gq * CH + col) = r;
}

extern "C" void kernel_launch(void* const* d_in, const int* in_sizes, int n_in,
                              void* d_out, int out_size, void* d_ws, size_t ws_size,
                              hipStream_t stream) {
  const float* verts = (const float*)d_in[0];
  const float* feat  = (const float*)d_in[1];
  const int*   sidx  = (const int*)d_in[2];
  float* outV = (float*)d_out;                          // [BATCH, QN, 3]
  float* outF = (float*)d_out + (size_t)BATCH * QN * 3; // [BATCH, QN, CH]
  int4*  nbr  = (int4*)d_ws;                            // 8192 * 16 B = 128 KB

  knn_scan_kernel<<<dim3(BATCH * SBLOCKS_PER_BATCH), dim3(SBLOCK), 0, stream>>>(
      verts, sidx, nbr, outV);
  knn_gather_kernel<<<dim3(BATCH * QN / GQPB), dim3(GBLOCK), 0, stream>>>(
      feat, nbr, outF);
}